// Round 1
// baseline (171.080 us; speedup 1.0000x reference)
//
#include <hip/hip_runtime.h>
#include <math.h>

#define N_TOK   8192
#define DIM     2048
#define NE      64
#define TOPK    4
#define KSPLIT  4
#define KPER    (DIM / KSPLIT)   /* 512 */
#define KC      32
#define TT      64               /* tokens per tile */
#define NTILE   (N_TOK / TT)     /* 128 */

// ---- workspace layout (float offsets) ----
#define OFF_PARTIAL 0                      /* KSPLIT*N_TOK*NE = 2097152 floats */
#define OFF_LOGITS  2097152                /* N_TOK*NE = 524288 */
#define OFF_MAXV    2621440                /* N_TOK */
#define OFF_DENOM   2629632                /* N_TOK */
#define OFF_W1      2637824                /* N_TOK */
#define OFF_C1      2646016                /* N_TOK ints */
#define OFF_CNT     2654208                /* NE ints */
#define OFF_FLAG    2654272                /* 1 int  */
#define OFF_WTMP    2654336                /* N_TOK*TOPK floats (fallback only) */

// K-split partial GEMM: partial[split][token][expert] = sum over K-slice of x.W^T
__global__ __launch_bounds__(256, 2)
void k_gemm(const float* __restrict__ x, const float* __restrict__ W,
            float* __restrict__ partial) {
    const int tile  = blockIdx.x;           // 0..NTILE-1
    const int split = blockIdx.y;           // 0..KSPLIT-1
    const int t0    = tile * TT;
    const int kbase = split * KPER;

    __shared__ __align__(16) float xs[KC][TT + 4];  // [k][token], stride 68 (272B, 16B-aligned rows)
    __shared__ __align__(16) float wl[KC][NE + 4];  // [k][expert]

    const int tid = threadIdx.x;
    const int tm  = tid & 15;               // token group -> tokens 4*tm..4*tm+3
    const int te  = tid >> 4;               // expert group -> experts 4*te..4*te+3
    const int c4  = tid & 7;                // k-float4 index for staging
    const int r   = tid >> 3;               // 0..31 staging row

    float acc[4][4];
    #pragma unroll
    for (int i = 0; i < 4; ++i)
        #pragma unroll
        for (int j = 0; j < 4; ++j) acc[i][j] = 0.0f;

    for (int kc = 0; kc < KPER; kc += KC) {
        __syncthreads();
        #pragma unroll
        for (int p = 0; p < 2; ++p) {
            const int row = p * 32 + r;     // 0..63
            const float4 xv = *reinterpret_cast<const float4*>(
                x + (size_t)(t0 + row) * DIM + kbase + kc + c4 * 4);
            xs[c4 * 4 + 0][row] = xv.x;
            xs[c4 * 4 + 1][row] = xv.y;
            xs[c4 * 4 + 2][row] = xv.z;
            xs[c4 * 4 + 3][row] = xv.w;
            const float4 wv = *reinterpret_cast<const float4*>(
                W + (size_t)row * DIM + kbase + kc + c4 * 4);
            wl[c4 * 4 + 0][row] = wv.x;
            wl[c4 * 4 + 1][row] = wv.y;
            wl[c4 * 4 + 2][row] = wv.z;
            wl[c4 * 4 + 3][row] = wv.w;
        }
        __syncthreads();
        #pragma unroll
        for (int k = 0; k < KC; ++k) {
            const float4 xv = *reinterpret_cast<const float4*>(&xs[k][tm * 4]);
            const float4 wv = *reinterpret_cast<const float4*>(&wl[k][te * 4]);
            const float xa[4] = {xv.x, xv.y, xv.z, xv.w};
            const float wa[4] = {wv.x, wv.y, wv.z, wv.w};
            #pragma unroll
            for (int i = 0; i < 4; ++i)
                #pragma unroll
                for (int j = 0; j < 4; ++j)
                    acc[i][j] = fmaf(xa[i], wa[j], acc[i][j]);
        }
    }

    float* base = partial + ((size_t)split * N_TOK + t0) * NE;
    #pragma unroll
    for (int i = 0; i < 4; ++i) {
        float4 v = make_float4(acc[i][0], acc[i][1], acc[i][2], acc[i][3]);
        *reinterpret_cast<float4*>(base + (size_t)(tm * 4 + i) * NE + te * 4) = v;
    }
}

// Per-row: combine partials (fixed order -> deterministic), +bias, argmax (first-index
// tie-break like jnp.argmax), softmax max/denominator, per-expert first-choice counts.
__global__ __launch_bounds__(256)
void k_row(const float* __restrict__ partial, const float* __restrict__ bias,
           float* __restrict__ logits, float* __restrict__ maxv,
           float* __restrict__ denomv, float* __restrict__ w1,
           int* __restrict__ c1, int* __restrict__ cnt) {
    const int row = blockIdx.x * 4 + (threadIdx.x >> 6);
    const int e   = threadIdx.x & 63;
    float l = bias[e];
    #pragma unroll
    for (int s = 0; s < KSPLIT; ++s)
        l += partial[((size_t)s * N_TOK + row) * NE + e];
    logits[(size_t)row * NE + e] = l;

    float v = l; int idx = e;
    #pragma unroll
    for (int off = 32; off; off >>= 1) {
        const float ov = __shfl_xor(v, off);
        const int   oi = __shfl_xor(idx, off);
        if (ov > v || (ov == v && oi < idx)) { v = ov; idx = oi; }
    }
    float p = expf(l - v);
    float s = p;
    #pragma unroll
    for (int off = 32; off; off >>= 1) s += __shfl_xor(s, off);

    if (e == 0) {
        maxv[row]   = v;
        denomv[row] = s;
        c1[row]     = idx;
        w1[row]     = 1.0f / s;       // softmax score at the argmax: exp(0)/denom
        atomicAdd(&cnt[idx], 1);
    }
}

// Fast-path check: no expert ever fills iff TOPK*n_e <= cap for all e.
__global__ void k_flag(const int* __restrict__ cnt, const int* __restrict__ tc,
                       int* __restrict__ flag) {
    const int e = threadIdx.x;             // 64 threads
    const int cap = tc[0] / TOPK;
    const bool bad = (TOPK * cnt[e] > cap);
    const unsigned long long m = __ballot(bad);
    if (e == 0) flag[0] = (m == 0ull) ? 1 : 0;
}

// Fast path: every token takes its argmax 4x; normalized weight = w/(4w+1e-8).
__global__ __launch_bounds__(256)
void k_fast(const int* __restrict__ flag, const int* __restrict__ c1,
            const float* __restrict__ w1, float* __restrict__ out) {
    if (!flag[0]) return;
    const int b = blockIdx.x * 256 + threadIdx.x;
    const float se = (float)c1[b];
    const float w  = w1[b];
    const float wn = w / (4.0f * w + 1e-8f);
    *reinterpret_cast<float4*>(out + (size_t)b * 4) = make_float4(se, se, se, se);
    *reinterpret_cast<float4*>(out + (size_t)N_TOK * TOPK + (size_t)b * 4) =
        make_float4(wn, wn, wn, wn);
}

// Exact serial fallback (rarely taken): one wave, lane = expert. Selection rule
// (zaps proven irrelevant): argmax of original logits among experts w/ capacity.
__global__ void k_fallback(const int* __restrict__ flag, const float* __restrict__ logits,
                           const float* __restrict__ maxv, const float* __restrict__ denomv,
                           const int* __restrict__ tc, float* __restrict__ out,
                           float* __restrict__ wtmp) {
    if (flag[0]) return;
    const int e = threadIdx.x;             // 64 threads
    const int cap = tc[0] / TOPK;
    int rem = cap;
    for (int k = 0; k < TOPK; ++k) {
        for (int b = 0; b < N_TOK; ++b) {
            const float l = logits[(size_t)b * NE + e];
            float v = (rem > 0) ? l : -INFINITY;
            int idx = e;
            #pragma unroll
            for (int off = 32; off; off >>= 1) {
                const float ov = __shfl_xor(v, off);
                const int   oi = __shfl_xor(idx, off);
                if (ov > v || (ov == v && oi < idx)) { v = ov; idx = oi; }
            }
            const bool ok = (v != -INFINITY);
            if (ok && e == idx) rem -= 1;
            const float lc = __shfl(l, idx);
            if (e == 0) {
                out[(size_t)b * TOPK + k]  = ok ? (float)idx : -1.0f;
                wtmp[(size_t)b * TOPK + k] = ok ? expf(lc - maxv[b]) / denomv[b] : 0.0f;
            }
        }
    }
    __syncthreads();
    for (int b = e; b < N_TOK; b += 64) {
        const float w0 = wtmp[b * 4 + 0], w1_ = wtmp[b * 4 + 1];
        const float w2 = wtmp[b * 4 + 2], w3 = wtmp[b * 4 + 3];
        const float s = ((w0 + w1_) + w2) + w3 + 1e-8f;
        out[N_TOK * TOPK + b * 4 + 0] = w0 / s;
        out[N_TOK * TOPK + b * 4 + 1] = w1_ / s;
        out[N_TOK * TOPK + b * 4 + 2] = w2 / s;
        out[N_TOK * TOPK + b * 4 + 3] = w3 / s;
    }
}

extern "C" void kernel_launch(void* const* d_in, const int* in_sizes, int n_in,
                              void* d_out, int out_size, void* d_ws, size_t ws_size,
                              hipStream_t stream) {
    const float* x    = (const float*)d_in[0];
    const float* W    = (const float*)d_in[1];
    const float* bias = (const float*)d_in[2];
    const int*   tc   = (const int*)d_in[3];

    float* ws      = (float*)d_ws;
    float* partial = ws + OFF_PARTIAL;
    float* logits  = ws + OFF_LOGITS;
    float* maxv    = ws + OFF_MAXV;
    float* denomv  = ws + OFF_DENOM;
    float* w1      = ws + OFF_W1;
    int*   c1      = (int*)(ws + OFF_C1);
    int*   cnt     = (int*)(ws + OFF_CNT);
    int*   flag    = (int*)(ws + OFF_FLAG);
    float* wtmp    = ws + OFF_WTMP;
    float* out     = (float*)d_out;

    // zero cnt[64] + flag[1] (ws is poisoned 0xAA before every call)
    hipMemsetAsync(cnt, 0, (NE + 16) * sizeof(int), stream);

    dim3 g1(NTILE, KSPLIT);
    k_gemm<<<g1, 256, 0, stream>>>(x, W, partial);
    k_row<<<N_TOK / 4, 256, 0, stream>>>(partial, bias, logits, maxv, denomv, w1, c1, cnt);
    k_flag<<<1, 64, 0, stream>>>(cnt, tc, flag);
    k_fast<<<N_TOK / 256, 256, 0, stream>>>(flag, c1, w1, out);
    k_fallback<<<1, 64, 0, stream>>>(flag, logits, maxv, denomv, tc, out, wtmp);
}

// Round 2
// 164.275 us; speedup vs baseline: 1.0414x; 1.0414x over previous
//
#include <hip/hip_runtime.h>
#include <math.h>

#define N_TOK   8192
#define DIM     2048
#define NE      64
#define TOPK    4
#define KSPLIT  4
#define KPER    (DIM / KSPLIT)   /* 512 */
#define TPW     4                /* tokens per wave */
#define WPB     4                /* waves per block */
#define TPB     (TPW * WPB)      /* 16 tokens per block */
#define NTILE   (N_TOK / TPB)    /* 512 */

// ---- workspace layout (float offsets) ----
#define OFF_PARTIAL 0                              /* KSPLIT*N_TOK*NE = 2097152 */
#define OFF_LOGITS  (KSPLIT * N_TOK * NE)          /* N_TOK*NE = 524288 */
#define OFF_MAXV    (OFF_LOGITS + N_TOK * NE)
#define OFF_DENOM   (OFF_MAXV + N_TOK)
#define OFF_W1      (OFF_DENOM + N_TOK)
#define OFF_C1      (OFF_W1 + N_TOK)               /* ints */
#define OFF_WT2     (OFF_C1 + N_TOK)               /* NE*DIM = 131072 */
#define OFF_WTMP    (OFF_WT2 + NE * DIM)           /* N_TOK*TOPK (fallback only) */

// Transpose W (64,2048) -> Wt2[kq][e][4] so the GEMV inner loop does one
// coalesced dwordx4 per lane per 4-k chunk.
__global__ __launch_bounds__(256)
void k_wt(const float* __restrict__ W, float* __restrict__ wt2) {
    const int tid = blockIdx.x * 256 + threadIdx.x;   // 0..32767
    const int e   = tid & 63;
    const int kq  = tid >> 6;                          // 0..511
    const float4 v = *reinterpret_cast<const float4*>(W + (size_t)e * DIM + kq * 4);
    *reinterpret_cast<float4*>(wt2 + (size_t)kq * (NE * 4) + e * 4) = v;
}

// LDS-free GEMV: lane = expert, wave owns TPW tokens, x rows via wave-uniform
// (scalar) loads, W via coalesced dwordx4 from L2. 2048 blocks -> 8 blocks/CU,
// ~20 VGPRs -> full occupancy, no barriers.
__global__ __launch_bounds__(256, 8)
void k_gemv(const float* __restrict__ x, const float* __restrict__ wt2,
            float* __restrict__ partial) {
    const int lane  = threadIdx.x & 63;
    const int wv    = __builtin_amdgcn_readfirstlane((int)(threadIdx.x >> 6));
    const int split = blockIdx.y;
    const int t0    = blockIdx.x * TPB + wv * TPW;
    const int kbase = split * KPER;

    const float* xr = x + (size_t)t0 * DIM + kbase;        // wave-uniform
    const float* wp = wt2 + (size_t)(kbase >> 2) * (NE * 4) + lane * 4;

    float a0 = 0.0f, a1 = 0.0f, a2 = 0.0f, a3 = 0.0f;

    #pragma unroll 4
    for (int k = 0; k < KPER; k += 4) {
        const float4 w4 = *reinterpret_cast<const float4*>(wp + (size_t)k * NE);
        const float4 xa = *reinterpret_cast<const float4*>(xr + 0 * DIM + k);
        const float4 xb = *reinterpret_cast<const float4*>(xr + 1 * DIM + k);
        const float4 xc = *reinterpret_cast<const float4*>(xr + 2 * DIM + k);
        const float4 xd = *reinterpret_cast<const float4*>(xr + 3 * DIM + k);
        a0 = fmaf(xa.x, w4.x, a0); a0 = fmaf(xa.y, w4.y, a0);
        a0 = fmaf(xa.z, w4.z, a0); a0 = fmaf(xa.w, w4.w, a0);
        a1 = fmaf(xb.x, w4.x, a1); a1 = fmaf(xb.y, w4.y, a1);
        a1 = fmaf(xb.z, w4.z, a1); a1 = fmaf(xb.w, w4.w, a1);
        a2 = fmaf(xc.x, w4.x, a2); a2 = fmaf(xc.y, w4.y, a2);
        a2 = fmaf(xc.z, w4.z, a2); a2 = fmaf(xc.w, w4.w, a2);
        a3 = fmaf(xd.x, w4.x, a3); a3 = fmaf(xd.y, w4.y, a3);
        a3 = fmaf(xd.z, w4.z, a3); a3 = fmaf(xd.w, w4.w, a3);
    }

    float* pb = partial + ((size_t)split * N_TOK + t0) * NE + lane;
    pb[0 * NE] = a0;
    pb[1 * NE] = a1;
    pb[2 * NE] = a2;
    pb[3 * NE] = a3;
}

// Per-row: combine partials in fixed split order (bit-identical to r1), +bias,
// argmax (first-index tie-break), softmax max/denominator, top-1 score.
__global__ __launch_bounds__(256)
void k_row(const float* __restrict__ partial, const float* __restrict__ bias,
           float* __restrict__ logits, float* __restrict__ maxv,
           float* __restrict__ denomv, float* __restrict__ w1,
           int* __restrict__ c1) {
    const int row = blockIdx.x * 4 + (threadIdx.x >> 6);
    const int e   = threadIdx.x & 63;
    float l = bias[e];
    #pragma unroll
    for (int s = 0; s < KSPLIT; ++s)
        l += partial[((size_t)s * N_TOK + row) * NE + e];
    logits[(size_t)row * NE + e] = l;

    float v = l; int idx = e;
    #pragma unroll
    for (int off = 32; off; off >>= 1) {
        const float ov = __shfl_xor(v, off);
        const int   oi = __shfl_xor(idx, off);
        if (ov > v || (ov == v && oi < idx)) { v = ov; idx = oi; }
    }
    float p = expf(l - v);
    float s = p;
    #pragma unroll
    for (int off = 32; off; off >>= 1) s += __shfl_xor(s, off);

    if (e == 0) {
        maxv[row]   = v;
        denomv[row] = s;
        c1[row]     = idx;
        w1[row]     = 1.0f / s;   // score at argmax: exp(0)/denom
    }
}

// Fused decide: per-block LDS histogram of first choices -> capacity flag;
// fast path writes, or block-0 serial fallback (exact).
__global__ __launch_bounds__(256)
void k_decide(const int* __restrict__ c1, const float* __restrict__ w1,
              const float* __restrict__ logits, const float* __restrict__ maxv,
              const float* __restrict__ denomv, const int* __restrict__ tc,
              float* __restrict__ out, float* __restrict__ wtmp) {
    __shared__ int hist[NE];
    __shared__ int flagS;
    const int tid = threadIdx.x;
    if (tid < NE) hist[tid] = 0;
    __syncthreads();
    for (int i = tid; i < N_TOK; i += 256) atomicAdd(&hist[c1[i]], 1);
    __syncthreads();
    const int cap = tc[0] / TOPK;
    if (tid < NE) {
        const bool bad = (TOPK * hist[tid] > cap);
        const unsigned long long m = __ballot(bad);
        if (tid == 0) flagS = (m == 0ull) ? 1 : 0;
    }
    __syncthreads();

    if (flagS) {
        const int b = blockIdx.x * 256 + tid;
        const float se = (float)c1[b];
        const float w  = w1[b];
        const float wn = w / (4.0f * w + 1e-8f);
        *reinterpret_cast<float4*>(out + (size_t)b * 4) = make_float4(se, se, se, se);
        *reinterpret_cast<float4*>(out + (size_t)N_TOK * TOPK + (size_t)b * 4) =
            make_float4(wn, wn, wn, wn);
        return;
    }

    if (blockIdx.x != 0) return;
    // exact serial fallback: argmax of original logits among experts w/ capacity
    if (tid < 64) {
        const int e = tid;
        int rem = cap;
        for (int k = 0; k < TOPK; ++k) {
            for (int b = 0; b < N_TOK; ++b) {
                const float l = logits[(size_t)b * NE + e];
                float v = (rem > 0) ? l : -INFINITY;
                int idx = e;
                #pragma unroll
                for (int off = 32; off; off >>= 1) {
                    const float ov = __shfl_xor(v, off);
                    const int   oi = __shfl_xor(idx, off);
                    if (ov > v || (ov == v && oi < idx)) { v = ov; idx = oi; }
                }
                const bool ok = (v != -INFINITY);
                if (ok && e == idx) rem -= 1;
                const float lc = __shfl(l, idx);
                if (e == 0) {
                    out[(size_t)b * TOPK + k]  = ok ? (float)idx : -1.0f;
                    wtmp[(size_t)b * TOPK + k] = ok ? expf(lc - maxv[b]) / denomv[b] : 0.0f;
                }
            }
        }
    }
    __syncthreads();
    for (int b = tid; b < N_TOK; b += 256) {
        const float w0 = wtmp[b * 4 + 0], w1_ = wtmp[b * 4 + 1];
        const float w2 = wtmp[b * 4 + 2], w3 = wtmp[b * 4 + 3];
        const float s = ((w0 + w1_) + w2) + w3 + 1e-8f;
        out[N_TOK * TOPK + b * 4 + 0] = w0 / s;
        out[N_TOK * TOPK + b * 4 + 1] = w1_ / s;
        out[N_TOK * TOPK + b * 4 + 2] = w2 / s;
        out[N_TOK * TOPK + b * 4 + 3] = w3 / s;
    }
}

extern "C" void kernel_launch(void* const* d_in, const int* in_sizes, int n_in,
                              void* d_out, int out_size, void* d_ws, size_t ws_size,
                              hipStream_t stream) {
    const float* x    = (const float*)d_in[0];
    const float* W    = (const float*)d_in[1];
    const float* bias = (const float*)d_in[2];
    const int*   tc   = (const int*)d_in[3];

    float* ws      = (float*)d_ws;
    float* partial = ws + OFF_PARTIAL;
    float* logits  = ws + OFF_LOGITS;
    float* maxv    = ws + OFF_MAXV;
    float* denomv  = ws + OFF_DENOM;
    float* w1      = ws + OFF_W1;
    int*   c1      = (int*)(ws + OFF_C1);
    float* wt2     = ws + OFF_WT2;
    float* wtmp    = ws + OFF_WTMP;
    float* out     = (float*)d_out;

    k_wt<<<(NE * DIM / 4) / 256, 256, 0, stream>>>(W, wt2);
    dim3 g(NTILE, KSPLIT);
    k_gemv<<<g, 256, 0, stream>>>(x, wt2, partial);
    k_row<<<N_TOK / 4, 256, 0, stream>>>(partial, bias, logits, maxv, denomv, w1, c1);
    k_decide<<<N_TOK / 256, 256, 0, stream>>>(c1, w1, logits, maxv, denomv, tc, out, wtmp);
}